// Round 17
// baseline (246.845 us; speedup 1.0000x reference)
//
#include <hip/hip_runtime.h>
#include <stdint.h>

typedef __bf16 bf16x8 __attribute__((ext_vector_type(8)));
typedef float f32x4 __attribute__((ext_vector_type(4)));
typedef float f32x16 __attribute__((ext_vector_type(16)));
typedef uint16_t u16;
typedef uint32_t u32;
typedef u16 u16x8 __attribute__((ext_vector_type(8)));
typedef u16 u16x4 __attribute__((ext_vector_type(4)));

#define NSTEP 63   // 2*32-1 diagonal steps

// ---- workspace layout (bytes) ----
#define IMG_SK_BYTES (128ull*NSTEP*4096ull*2ull)
#define WPACK_OFF    IMG_SK_BYTES
#define TMP_OFF      (WPACK_OFF + 8ull*2ull*25ull*64ull*8ull*2ull)

// ---- helpers ----
__device__ __forceinline__ u16 f2bf(float f) {
  u32 u = __builtin_bit_cast(u32, f);
  return (u16)((u + 0x7fffu + ((u >> 16) & 1u)) >> 16);   // RNE
}
__device__ __forceinline__ float bf2f(u16 h) {
  u32 u = ((u32)h) << 16;
  return __builtin_bit_cast(float, u);
}
__device__ __forceinline__ float sigf(float x) {
  float e = __builtin_amdgcn_exp2f(-1.442695041f * x);
  return __builtin_amdgcn_rcpf(1.0f + e);
}
__device__ __forceinline__ float tanhf_fast(float x) {
  x = fminf(fmaxf(x, -20.f), 20.f);       // clamp: avoid inf-inf NaN
  float e = __builtin_amdgcn_exp2f(2.885390082f * x);
  return (e - 1.0f) * __builtin_amdgcn_rcpf(e + 1.0f);
}
__device__ __forceinline__ void gload_lds16(const void* g, char* smem, u32 lds_off) {
  __builtin_amdgcn_global_load_lds(
      (const __attribute__((address_space(1))) uint32_t*)g,
      (__attribute__((address_space(3))) uint32_t*)(smem + lds_off), 16, 0, 0);
}
__device__ __forceinline__ bf16x8 ldsv(const char* smem, u32 off) {
  return *reinterpret_cast<const bf16x8*>(smem + off);    // ds_read_b128
}

// =====================================================================
// Kernel 1: pre-skew image (R1..R16-passing verbatim).
// =====================================================================
__global__ __launch_bounds__(256) void k_prepack_img(
    const float* __restrict__ image, u16* __restrict__ img_sk) {
  __shared__ float tile[128 * 33];
  const int b = blockIdx.x >> 5, n = blockIdx.x & 31;
  const int tid = threadIdx.x;
  for (int rep = 0; rep < 16; ++rep) {
    int idx = rep * 256 + tid;
    int c = idx >> 5, col = idx & 31;
    tile[c * 33 + col] = image[(((b * 128 + c) * 32 + n) << 5) + col];
  }
  __syncthreads();
  const int m = n & 7;
  for (int rep = 0; rep < 4; ++rep) {
    int idx = rep * 256 + tid;
    if (idx < NSTEP * 16) {
      int t = idx >> 4, six = idx & 15;
      bool valid = (t >= n) && (t < n + 32);
      u16x8 v;
      #pragma unroll
      for (int j = 0; j < 8; ++j) {
        int c = ((six ^ m) << 3) | j;              // inverse of read-side XOR swizzle
        v[j] = valid ? f2bf(tile[c * 33 + (t - n)]) : (u16)0;
      }
      *reinterpret_cast<u16x8*>(img_sk + (size_t)(b * NSTEP + t) * 4096 + n * 128 + six * 8) = v;
    }
  }
}

// =====================================================================
// Kernel 2: pack W as 32x32x16 A-fragments, K=400 (R16-passing verbatim).
// =====================================================================
__global__ __launch_bounds__(256) void k_prepack_w(
    const float* __restrict__ stos_w, const float* __restrict__ itos_w,
    const float* __restrict__ itos_b, const float* __restrict__ stos_b,
    u16* __restrict__ wp) {
  int pos = blockIdx.x * 256 + threadIdx.x;        // [w][mt][kappa][lane][j]
  if (pos >= 204800) return;
  int j = pos & 7, l = (pos >> 3) & 63;
  int idx2 = pos >> 9;
  int kap = idx2 % 25;
  int wm = idx2 / 25;
  int mt = wm & 1, w = wm >> 1;
  int row32 = l & 31, kh = l >> 5;
  int k = kap * 16 + kh * 8 + j;
  int q = row32 & 3, hb_ = (row32 >> 2) & 1, blk = row32 >> 3;
  int c = w * 16 + mt * 8 + hb_ * 4 + blk;
  int o = q * 128 + c;
  float v;
  if (k < 128)       v = stos_w[o * 256 + k * 2 + 0];
  else if (k < 256)  v = stos_w[o * 256 + (k - 128) * 2 + 1];
  else if (k < 384)  v = itos_w[o * 128 + (k - 256)];
  else if (k == 384) v = itos_b[o] + stos_b[o];
  else               v = 0.0f;
  wp[pos] = f2bf(v);
}

// =====================================================================
// Kernel 3: diagonal-LSTM scan, 32x32x16 (R16-passing) + WAVE-STAGGERED
// SEGMENT ROTATION: the 3 independent 8-slice segments (sh-h / h / img)
// execute in per-wave rotated order (w%3) so waves on a SIMD are never
// in the same phase -> LDS-read bursts of one wave fill the MFMA windows
// of the other (breaks the barrier-induced lockstep serialization).
// LDS map (static 131072 B, R16-verified).
// =====================================================================
__global__ __attribute__((amdgpu_waves_per_eu(2, 2)))
__launch_bounds__(512, 2) void k_scan(
    const u16* __restrict__ img_sk, const u16* __restrict__ wpack,
    const float* __restrict__ h0, const float* __restrict__ c0,
    u16* __restrict__ tmp) {
  __shared__ char smem[131072];
  const int b = blockIdx.x;
  const int tid = threadIdx.x;
  const int w = tid >> 6, lane = tid & 63;
  const int s = lane & 31, hi = lane >> 5;

  // ---- A-slices 0..19 into registers (160 regs) ----
  bf16x8 aw[2][20];
  #pragma unroll
  for (int mt = 0; mt < 2; ++mt)
    #pragma unroll
    for (int kp = 0; kp < 20; ++kp)
      aw[mt][kp] = *reinterpret_cast<const bf16x8*>(
          wpack + (size_t)(((w * 2 + mt) * 25 + kp) * 64 + lane) * 8);
  // A-slices 20..24 -> LDS (once; W constant)
  #pragma unroll
  for (int mt = 0; mt < 2; ++mt)
    #pragma unroll
    for (int kL = 0; kL < 5; ++kL)
      gload_lds16(wpack + (size_t)(((w * 2 + mt) * 25 + 20 + kL) * 64 + lane) * 8,
                  smem, 49152u + (u32)w * 10240u + (u32)(mt * 5 + kL) * 1024u);
  // preload imgbuf[0] (t=0)
  const u16* img_base = img_sk + (size_t)b * NSTEP * 4096;
  gload_lds16(img_base + (u32)tid * 8, smem, 32768u + (u32)w * 1024u);
  // ones-column B fragment constant: hi=0 chunk {1.0bf16,0...}, hi=1 zeros
  if (tid < 16) ((u16*)(smem + 16896))[tid] = (tid == 0) ? (u16)0x3F80 : (u16)0;
  // hbuf0 init: row 0 = zeros, rows 1..32 = h0 (swizzled) — verified formula
  for (int idx = tid; idx < 33 * 128; idx += 512) {
    int row = idx >> 7, c = idx & 127;
    u16 v = (row == 0) ? (u16)0 : f2bf(h0[c * 32 + (row - 1)]);
    u32 a = (u32)(row << 8) | (u32)((((c >> 3) ^ (row & 7)) << 4) | ((c & 7) << 1));
    *(u16*)(smem + a) = v;
  }
  // hbuf1 row 0 = zeros
  for (int idx = tid; idx < 128; idx += 512) {
    int c = idx;
    u32 a = 8448u + (u32)(((c >> 3) << 4) | ((c & 7) << 1));
    *(u16*)(smem + a) = (u16)0;
  }
  // c state: cst[mt][blk] for channel c = w*16+mt*8+hi*4+blk, col s
  float cst[2][4];
  #pragma unroll
  for (int mt = 0; mt < 2; ++mt)
    #pragma unroll
    for (int blk = 0; blk < 4; ++blk)
      cst[mt][blk] = c0[(w * 16 + mt * 8 + hi * 4 + blk) * 32 + s];

  // per-lane B bases (R16-verified)
  const u32 Bsh = ((u32)s << 8) + ((((u32)hi) ^ (u32)(s & 7)) << 4);             // rows s
  const u32 Bh  = ((u32)(s + 1) << 8) + ((((u32)hi) ^ (u32)((s + 1) & 7)) << 4); // rows s+1
  const u32 Wb0 = ((u32)(s + 1) << 8) + ((((u32)(w << 1)) ^ (u32)((s + 1) & 7)) << 4) + ((u32)hi << 3);
  const u32 aLb = 49152u + (u32)w * 10240u + (u32)lane * 16u;   // + (mt*5+kL)*1024
  const u32 tmpidx = (u32)(w * 512 + hi * 128 + s);             // + mt*256 + blk*32
  u16* tmpb = tmp + (size_t)b * NSTEP * 4096;
  const int rot = w % 3;                                        // wave-uniform rotation

  __syncthreads();   // drains init DMAs (vmcnt) + LDS writes

  f32x16 acc[2];
  u16 hb[2][4];

  #pragma unroll 1
  for (int t = 0; t < NSTEP; ++t) {
    // deferred tmp stores for step t-1
    if (t) {
      #pragma unroll
      for (int mt = 0; mt < 2; ++mt)
        #pragma unroll
        for (int blk = 0; blk < 4; ++blk)
          tmpb[(size_t)(t - 1) * 4096 + tmpidx + mt * 256 + blk * 32] = hb[mt][blk];
    }
    // prefetch next image column into the other imgbuf
    if (t < NSTEP - 1)
      gload_lds16(img_base + (size_t)(t + 1) * 4096 + (u32)tid * 8,
                  smem, 32768u + (u32)(((t + 1) & 1) << 13) + (u32)w * 1024u);

    const u32 hbb = (u32)((t & 1) ? 8448u : 0u);          // hbuf read base
    const u32 ib  = 32768u + (u32)((t & 1) << 13);

    __builtin_amdgcn_s_setprio(1);
    // ---- bias slice (kap=24): acc = bias via ones column, C=0 ----
    {
      bf16x8 bOnes = ldsv(smem, 16896u + ((u32)hi << 4));
      f32x16 z = {};
      #pragma unroll
      for (int mt = 0; mt < 2; ++mt) {
        bf16x8 a = ldsv(smem, aLb + (u32)(mt * 5 + 4) * 1024u);
        acc[mt] = __builtin_amdgcn_mfma_f32_32x32x16_bf16(a, bOnes, z, 0, 0, 0);
      }
    }
    // ---- segments (each 8 slices), executed in per-wave rotated order ----
    auto segH1 = [&]() {   // shifted h: global kp 0..7
      #pragma unroll
      for (int kp = 0; kp < 8; ++kp) {
        bf16x8 bv = ldsv(smem, hbb + (Bsh ^ ((u32)kp << 5)));
        #pragma unroll
        for (int mt = 0; mt < 2; ++mt)
          acc[mt] = __builtin_amdgcn_mfma_f32_32x32x16_bf16(aw[mt][kp], bv, acc[mt], 0, 0, 0);
      }
    };
    auto segH2 = [&]() {   // h: global kp 8..15
      #pragma unroll
      for (int kp = 0; kp < 8; ++kp) {
        bf16x8 bv = ldsv(smem, hbb + (Bh ^ ((u32)kp << 5)));
        #pragma unroll
        for (int mt = 0; mt < 2; ++mt)
          acc[mt] = __builtin_amdgcn_mfma_f32_32x32x16_bf16(aw[mt][8 + kp], bv, acc[mt], 0, 0, 0);
      }
    };
    auto segIMG = [&]() {  // image: global kp 16..23 (kap 20..23 from LDS)
      #pragma unroll
      for (int kp = 0; kp < 8; ++kp) {
        bf16x8 bv = ldsv(smem, ib + (Bsh ^ ((u32)kp << 5)));
        #pragma unroll
        for (int mt = 0; mt < 2; ++mt) {
          bf16x8 a = (kp < 4) ? aw[mt][16 + kp]
                              : ldsv(smem, aLb + (u32)(mt * 5 + (kp - 4)) * 1024u);
          acc[mt] = __builtin_amdgcn_mfma_f32_32x32x16_bf16(a, bv, acc[mt], 0, 0, 0);
        }
      }
    };
    if (rot == 0)      { segH1(); segH2(); segIMG(); }
    else if (rot == 1) { segH2(); segIMG(); segH1(); }
    else               { segIMG(); segH1(); segH2(); }
    __builtin_amdgcn_s_setprio(0);

    // ---- activations: acc[mt] regs = q + blk*4 (q: i,g,f,o) ----
    #pragma unroll
    for (int mt = 0; mt < 2; ++mt)
      #pragma unroll
      for (int blk = 0; blk < 4; ++blk) {
        float gi = acc[mt][blk * 4 + 0];
        float gg = acc[mt][blk * 4 + 1];
        float gf = acc[mt][blk * 4 + 2];
        float go = acc[mt][blk * 4 + 3];
        float si = sigf(gi);
        float tg = tanhf_fast(gg);
        float sf = sigf(gf);
        float so = sigf(go);
        float cp = cst[mt][blk];
        cst[mt][blk] = sf * cp + si * tg;   // c_new
        hb[mt][blk] = f2bf(cp * so);        // h_new = c_prev * sig(o)
      }
    // ---- h-write: 2 x ds_write_b64 (4 contiguous channels each) ----
    {
      const u32 hwb = (u32)((t & 1) ? 0u : 8448u);
      u16x4 p0 = {hb[0][0], hb[0][1], hb[0][2], hb[0][3]};
      u16x4 p1 = {hb[1][0], hb[1][1], hb[1][2], hb[1][3]};
      *(u16x4*)(smem + (hwb + Wb0)) = p0;
      *(u16x4*)(smem + ((hwb + Wb0) ^ 16u)) = p1;
    }
    __syncthreads();   // single barrier: h(t) + img(t+1) visible for t+1
  }
  // final step's tmp stores
  #pragma unroll
  for (int mt = 0; mt < 2; ++mt)
    #pragma unroll
    for (int blk = 0; blk < 4; ++blk)
      tmpb[(size_t)(NSTEP - 1) * 4096 + tmpidx + mt * 256 + blk * 32] = hb[mt][blk];
}

// =====================================================================
// Kernel 4: unskew-transpose tmp -> out (R3..R16-passing verbatim).
// =====================================================================
__global__ __launch_bounds__(256) void k_unskew(
    const u16* __restrict__ tmp, float* __restrict__ out) {
  __shared__ float tile[8192];                 // [cl][s][j] = cl*1024+s*32+j
  const int b = blockIdx.x >> 4, c8 = blockIdx.x & 15;
  const int tid = threadIdx.x;
  const int cl = tid >> 5, s = tid & 31;
  const u16* tb = tmp + (size_t)b * NSTEP * 4096 + (u32)(c8 * 256 + cl * 32 + s);
  for (int t = 0; t < NSTEP; ++t) {
    u16 v = tb[t * 4096];
    int j = t - s;
    if ((unsigned)j < 32u) tile[cl * 1024 + s * 32 + j] = bf2f(v);
  }
  __syncthreads();
  float* op = out + (size_t)b * 131072 + (u32)(c8 * 8192);
  #pragma unroll
  for (int rep = 0; rep < 8; ++rep)
    *(f32x4*)(op + rep * 1024 + tid * 4) = *(const f32x4*)(tile + rep * 1024 + tid * 4);
}

// =====================================================================
extern "C" void kernel_launch(void* const* d_in, const int* in_sizes, int n_in,
                              void* d_out, int out_size, void* d_ws, size_t ws_size,
                              hipStream_t stream) {
  const float* image  = (const float*)d_in[0];
  const float* itos_w = (const float*)d_in[1];
  const float* itos_b = (const float*)d_in[2];
  const float* stos_w = (const float*)d_in[3];
  const float* stos_b = (const float*)d_in[4];
  const float* h0     = (const float*)d_in[5];
  const float* c0     = (const float*)d_in[6];
  (void)in_sizes; (void)n_in; (void)out_size; (void)ws_size;

  char* ws = (char*)d_ws;
  u16*   img_sk = (u16*)(ws);
  u16*   wpack  = (u16*)(ws + WPACK_OFF);
  u16*   tmp    = (u16*)(ws + TMP_OFF);

  k_prepack_img <<<4096, 256, 0, stream>>>(image, img_sk);
  k_prepack_w   <<<800, 256, 0, stream>>>(stos_w, itos_w, itos_b, stos_b, wpack);
  k_scan        <<<128, 512, 0, stream>>>(img_sk, wpack, h0, c0, tmp);
  k_unskew      <<<2048, 256, 0, stream>>>(tmp, (float*)d_out);
}

// Round 18
// 241.584 us; speedup vs baseline: 1.0218x; 1.0218x over previous
//
#include <hip/hip_runtime.h>
#include <stdint.h>

typedef __bf16 bf16x8 __attribute__((ext_vector_type(8)));
typedef float f32x4 __attribute__((ext_vector_type(4)));
typedef float f32x16 __attribute__((ext_vector_type(16)));
typedef uint16_t u16;
typedef uint32_t u32;
typedef u16 u16x8 __attribute__((ext_vector_type(8)));
typedef u16 u16x4 __attribute__((ext_vector_type(4)));

#define NSTEP 63   // 2*32-1 diagonal steps

// ---- workspace layout (bytes) ----
// img_sk : [128][63][4096] bf16 (pre-skewed, pre-swizzled; R1-verified)
// wpack  : [8][2][25][64][8] bf16 (32x32x16 A-frags of W, K=400 incl bias col)
// tmp    : [128][63][128][32] bf16
#define IMG_SK_BYTES (128ull*NSTEP*4096ull*2ull)
#define WPACK_OFF    IMG_SK_BYTES
#define TMP_OFF      (WPACK_OFF + 8ull*2ull*25ull*64ull*8ull*2ull)

// ---- helpers ----
__device__ __forceinline__ u16 f2bf(float f) {
  u32 u = __builtin_bit_cast(u32, f);
  return (u16)((u + 0x7fffu + ((u >> 16) & 1u)) >> 16);   // RNE
}
__device__ __forceinline__ float bf2f(u16 h) {
  u32 u = ((u32)h) << 16;
  return __builtin_bit_cast(float, u);
}
__device__ __forceinline__ float sigf(float x) {
  float e = __builtin_amdgcn_exp2f(-1.442695041f * x);
  return __builtin_amdgcn_rcpf(1.0f + e);
}
__device__ __forceinline__ float tanhf_fast(float x) {
  x = fminf(fmaxf(x, -20.f), 20.f);       // clamp: avoid inf-inf NaN
  float e = __builtin_amdgcn_exp2f(2.885390082f * x);
  return (e - 1.0f) * __builtin_amdgcn_rcpf(e + 1.0f);
}
__device__ __forceinline__ void gload_lds16(const void* g, char* smem, u32 lds_off) {
  __builtin_amdgcn_global_load_lds(
      (const __attribute__((address_space(1))) uint32_t*)g,
      (__attribute__((address_space(3))) uint32_t*)(smem + lds_off), 16, 0, 0);
}
__device__ __forceinline__ bf16x8 ldsv(const char* smem, u32 off) {
  return *reinterpret_cast<const bf16x8*>(smem + off);    // ds_read_b128
}

// =====================================================================
// Kernel 1: pre-skew image (R1..R16-passing verbatim).
// =====================================================================
__global__ __launch_bounds__(256) void k_prepack_img(
    const float* __restrict__ image, u16* __restrict__ img_sk) {
  __shared__ float tile[128 * 33];
  const int b = blockIdx.x >> 5, n = blockIdx.x & 31;
  const int tid = threadIdx.x;
  for (int rep = 0; rep < 16; ++rep) {
    int idx = rep * 256 + tid;
    int c = idx >> 5, col = idx & 31;
    tile[c * 33 + col] = image[(((b * 128 + c) * 32 + n) << 5) + col];
  }
  __syncthreads();
  const int m = n & 7;
  for (int rep = 0; rep < 4; ++rep) {
    int idx = rep * 256 + tid;
    if (idx < NSTEP * 16) {
      int t = idx >> 4, six = idx & 15;
      bool valid = (t >= n) && (t < n + 32);
      u16x8 v;
      #pragma unroll
      for (int j = 0; j < 8; ++j) {
        int c = ((six ^ m) << 3) | j;              // inverse of read-side XOR swizzle
        v[j] = valid ? f2bf(tile[c * 33 + (t - n)]) : (u16)0;
      }
      *reinterpret_cast<u16x8*>(img_sk + (size_t)(b * NSTEP + t) * 4096 + n * 128 + six * 8) = v;
    }
  }
}

// =====================================================================
// Kernel 2: pack W as 32x32x16 A-fragments, K=400 (R16-passing verbatim).
// wp[w][mt][kappa][lane][j]: row32 = lane&31, k = kappa*16 + (lane>>5)*8 + j.
// Permutation: q=row32&3, hi=(row32>>2)&1, blk=row32>>3,
//              channel c = w*16 + mt*8 + hi*4 + blk, orig row o = q*128+c.
// K axis: [0,128)=stos_w[:,:,0], [128,256)=stos_w[:,:,1], [256,384)=itos_w,
//         k==384 -> itos_b+stos_b (ones-column bias), else 0.
// =====================================================================
__global__ __launch_bounds__(256) void k_prepack_w(
    const float* __restrict__ stos_w, const float* __restrict__ itos_w,
    const float* __restrict__ itos_b, const float* __restrict__ stos_b,
    u16* __restrict__ wp) {
  int pos = blockIdx.x * 256 + threadIdx.x;        // [w][mt][kappa][lane][j]
  if (pos >= 204800) return;
  int j = pos & 7, l = (pos >> 3) & 63;
  int idx2 = pos >> 9;
  int kap = idx2 % 25;
  int wm = idx2 / 25;
  int mt = wm & 1, w = wm >> 1;
  int row32 = l & 31, kh = l >> 5;
  int k = kap * 16 + kh * 8 + j;
  int q = row32 & 3, hb_ = (row32 >> 2) & 1, blk = row32 >> 3;
  int c = w * 16 + mt * 8 + hb_ * 4 + blk;
  int o = q * 128 + c;
  float v;
  if (k < 128)       v = stos_w[o * 256 + k * 2 + 0];
  else if (k < 256)  v = stos_w[o * 256 + (k - 128) * 2 + 1];
  else if (k < 384)  v = itos_w[o * 128 + (k - 256)];
  else if (k == 384) v = itos_b[o] + stos_b[o];
  else               v = 0.0f;
  wp[pos] = f2bf(v);
}

// =====================================================================
// Kernel 3: diagonal-LSTM scan, 32x32x16 MFMA shape (R16-passing verbatim).
//   8 waves x (M=64 as 2 m-tiles of 32); N=32 in ONE tile (no nt split).
//   K = 25 slices of 16; slices 0..19 in registers (160 regs), 20..24 in
//   LDS. Bias enters via slice 24 (ones column).
//   Single barrier/step + hbuf dbuf (R11/R12-verified skeleton).
// LDS map (static 131072 B):
//   [0,8448) hbuf0 | [8448,16896) hbuf1 | [16896,16928) ones const
//   [32768,49152) imgbuf x2 (8KB each)
//   [49152,131072) A-frags kap 20..24: w*10240 + (mt*5+(kap-20))*1024 + lane*16
// =====================================================================
__global__ __attribute__((amdgpu_waves_per_eu(2, 2)))
__launch_bounds__(512, 2) void k_scan(
    const u16* __restrict__ img_sk, const u16* __restrict__ wpack,
    const float* __restrict__ h0, const float* __restrict__ c0,
    u16* __restrict__ tmp) {
  __shared__ char smem[131072];
  const int b = blockIdx.x;
  const int tid = threadIdx.x;
  const int w = tid >> 6, lane = tid & 63;
  const int s = lane & 31, hi = lane >> 5;

  // ---- A-slices 0..19 into registers (160 regs) ----
  bf16x8 aw[2][20];
  #pragma unroll
  for (int mt = 0; mt < 2; ++mt)
    #pragma unroll
    for (int kp = 0; kp < 20; ++kp)
      aw[mt][kp] = *reinterpret_cast<const bf16x8*>(
          wpack + (size_t)(((w * 2 + mt) * 25 + kp) * 64 + lane) * 8);
  // A-slices 20..24 -> LDS (once; W constant)
  #pragma unroll
  for (int mt = 0; mt < 2; ++mt)
    #pragma unroll
    for (int kL = 0; kL < 5; ++kL)
      gload_lds16(wpack + (size_t)(((w * 2 + mt) * 25 + 20 + kL) * 64 + lane) * 8,
                  smem, 49152u + (u32)w * 10240u + (u32)(mt * 5 + kL) * 1024u);
  // preload imgbuf[0] (t=0) — R12-verbatim staging
  const u16* img_base = img_sk + (size_t)b * NSTEP * 4096;
  gload_lds16(img_base + (u32)tid * 8, smem, 32768u + (u32)w * 1024u);
  // ones-column B fragment constant: hi=0 chunk {1.0bf16,0...}, hi=1 zeros
  if (tid < 16) ((u16*)(smem + 16896))[tid] = (tid == 0) ? (u16)0x3F80 : (u16)0;
  // hbuf0 init: row 0 = zeros, rows 1..32 = h0 (swizzled) — verified formula
  for (int idx = tid; idx < 33 * 128; idx += 512) {
    int row = idx >> 7, c = idx & 127;
    u16 v = (row == 0) ? (u16)0 : f2bf(h0[c * 32 + (row - 1)]);
    u32 a = (u32)(row << 8) | (u32)((((c >> 3) ^ (row & 7)) << 4) | ((c & 7) << 1));
    *(u16*)(smem + a) = v;
  }
  // hbuf1 row 0 = zeros
  for (int idx = tid; idx < 128; idx += 512) {
    int c = idx;
    u32 a = 8448u + (u32)(((c >> 3) << 4) | ((c & 7) << 1));
    *(u16*)(smem + a) = (u16)0;
  }
  // c state: cst[mt][blk] for channel c = w*16+mt*8+hi*4+blk, col s
  float cst[2][4];
  #pragma unroll
  for (int mt = 0; mt < 2; ++mt)
    #pragma unroll
    for (int blk = 0; blk < 4; ++blk)
      cst[mt][blk] = c0[(w * 16 + mt * 8 + hi * 4 + blk) * 32 + s];

  // per-lane B bases: addr(kap) = base ^ (kap'<<5); chunk=(kap*2+hi)^(row&7)
  const u32 Bsh = ((u32)s << 8) + ((((u32)hi) ^ (u32)(s & 7)) << 4);          // rows s
  const u32 Bh  = ((u32)(s + 1) << 8) + ((((u32)hi) ^ (u32)((s + 1) & 7)) << 4); // rows s+1
  // h-write base (mt=0): row s+1, chunk (w*2)^((s+1)&7), intra hi*8; mt=1 -> ^16
  const u32 Wb0 = ((u32)(s + 1) << 8) + ((((u32)(w << 1)) ^ (u32)((s + 1) & 7)) << 4) + ((u32)hi << 3);
  const u32 aLb = 49152u + (u32)w * 10240u + (u32)lane * 16u;   // + (mt*5+kL)*1024
  const u32 tmpidx = (u32)(w * 512 + hi * 128 + s);             // + mt*256 + blk*32
  u16* tmpb = tmp + (size_t)b * NSTEP * 4096;

  __syncthreads();   // drains init DMAs (vmcnt) + LDS writes

  f32x16 acc[2];
  u16 hb[2][4];

  #pragma unroll 1
  for (int t = 0; t < NSTEP; ++t) {
    // deferred tmp stores for step t-1
    if (t) {
      #pragma unroll
      for (int mt = 0; mt < 2; ++mt)
        #pragma unroll
        for (int blk = 0; blk < 4; ++blk)
          tmpb[(size_t)(t - 1) * 4096 + tmpidx + mt * 256 + blk * 32] = hb[mt][blk];
    }
    // prefetch next image column into the other imgbuf (R12-verbatim)
    if (t < NSTEP - 1)
      gload_lds16(img_base + (size_t)(t + 1) * 4096 + (u32)tid * 8,
                  smem, 32768u + (u32)(((t + 1) & 1) << 13) + (u32)w * 1024u);

    const u32 hbb = (u32)((t & 1) ? 8448u : 0u);          // hbuf read base
    const u32 ib  = 32768u + (u32)((t & 1) << 13);

    __builtin_amdgcn_s_setprio(1);
    // ---- bias slice (kap=24) first: acc = bias via ones column, C=0 ----
    {
      bf16x8 bOnes = ldsv(smem, 16896u + ((u32)hi << 4));
      f32x16 z = {};
      #pragma unroll
      for (int mt = 0; mt < 2; ++mt) {
        bf16x8 a = ldsv(smem, aLb + (u32)(mt * 5 + 4) * 1024u);
        acc[mt] = __builtin_amdgcn_mfma_f32_32x32x16_bf16(a, bOnes, z, 0, 0, 0);
      }
    }
    // ---- K ladder: kap 0..23 ----
    #pragma unroll
    for (int kp = 0; kp < 24; ++kp) {
      bf16x8 bv;
      if (kp < 8)       bv = ldsv(smem, hbb + (Bsh ^ ((u32)kp << 5)));          // shifted h
      else if (kp < 16) bv = ldsv(smem, hbb + (Bh ^ ((u32)(kp - 8) << 5)));     // h
      else              bv = ldsv(smem, ib + (Bsh ^ ((u32)(kp - 16) << 5)));    // image
      #pragma unroll
      for (int mt = 0; mt < 2; ++mt) {
        bf16x8 a = (kp < 20) ? aw[mt][kp]
                             : ldsv(smem, aLb + (u32)(mt * 5 + (kp - 20)) * 1024u);
        acc[mt] = __builtin_amdgcn_mfma_f32_32x32x16_bf16(a, bv, acc[mt], 0, 0, 0);
      }
    }
    __builtin_amdgcn_s_setprio(0);

    // ---- activations: acc[mt] regs = q + blk*4 (q: i,g,f,o) ----
    #pragma unroll
    for (int mt = 0; mt < 2; ++mt)
      #pragma unroll
      for (int blk = 0; blk < 4; ++blk) {
        float gi = acc[mt][blk * 4 + 0];
        float gg = acc[mt][blk * 4 + 1];
        float gf = acc[mt][blk * 4 + 2];
        float go = acc[mt][blk * 4 + 3];
        float si = sigf(gi);
        float tg = tanhf_fast(gg);
        float sf = sigf(gf);
        float so = sigf(go);
        float cp = cst[mt][blk];
        cst[mt][blk] = sf * cp + si * tg;   // c_new
        hb[mt][blk] = f2bf(cp * so);        // h_new = c_prev * sig(o)
      }
    // ---- h-write: 2 x ds_write_b64 (4 contiguous channels each) ----
    {
      const u32 hwb = (u32)((t & 1) ? 0u : 8448u);
      u16x4 p0 = {hb[0][0], hb[0][1], hb[0][2], hb[0][3]};
      u16x4 p1 = {hb[1][0], hb[1][1], hb[1][2], hb[1][3]};
      *(u16x4*)(smem + (hwb + Wb0)) = p0;
      *(u16x4*)(smem + ((hwb + Wb0) ^ 16u)) = p1;
    }
    __syncthreads();   // single barrier: h(t) + img(t+1) visible for t+1
  }
  // final step's tmp stores
  #pragma unroll
  for (int mt = 0; mt < 2; ++mt)
    #pragma unroll
    for (int blk = 0; blk < 4; ++blk)
      tmpb[(size_t)(NSTEP - 1) * 4096 + tmpidx + mt * 256 + blk * 32] = hb[mt][blk];
}

// =====================================================================
// Kernel 4: unskew-transpose tmp -> out (R3..R16-passing verbatim).
// =====================================================================
__global__ __launch_bounds__(256) void k_unskew(
    const u16* __restrict__ tmp, float* __restrict__ out) {
  __shared__ float tile[8192];                 // [cl][s][j] = cl*1024+s*32+j
  const int b = blockIdx.x >> 4, c8 = blockIdx.x & 15;
  const int tid = threadIdx.x;
  const int cl = tid >> 5, s = tid & 31;
  const u16* tb = tmp + (size_t)b * NSTEP * 4096 + (u32)(c8 * 256 + cl * 32 + s);
  for (int t = 0; t < NSTEP; ++t) {
    u16 v = tb[t * 4096];
    int j = t - s;
    if ((unsigned)j < 32u) tile[cl * 1024 + s * 32 + j] = bf2f(v);
  }
  __syncthreads();
  float* op = out + (size_t)b * 131072 + (u32)(c8 * 8192);
  #pragma unroll
  for (int rep = 0; rep < 8; ++rep)
    *(f32x4*)(op + rep * 1024 + tid * 4) = *(const f32x4*)(tile + rep * 1024 + tid * 4);
}

// =====================================================================
extern "C" void kernel_launch(void* const* d_in, const int* in_sizes, int n_in,
                              void* d_out, int out_size, void* d_ws, size_t ws_size,
                              hipStream_t stream) {
  const float* image  = (const float*)d_in[0];
  const float* itos_w = (const float*)d_in[1];
  const float* itos_b = (const float*)d_in[2];
  const float* stos_w = (const float*)d_in[3];
  const float* stos_b = (const float*)d_in[4];
  const float* h0     = (const float*)d_in[5];
  const float* c0     = (const float*)d_in[6];
  (void)in_sizes; (void)n_in; (void)out_size; (void)ws_size;

  char* ws = (char*)d_ws;
  u16*   img_sk = (u16*)(ws);
  u16*   wpack  = (u16*)(ws + WPACK_OFF);
  u16*   tmp    = (u16*)(ws + TMP_OFF);

  k_prepack_img <<<4096, 256, 0, stream>>>(image, img_sk);
  k_prepack_w   <<<800, 256, 0, stream>>>(stos_w, itos_w, itos_b, stos_b, wpack);
  k_scan        <<<128, 512, 0, stream>>>(img_sk, wpack, h0, c0, tmp);
  k_unskew      <<<2048, 256, 0, stream>>>(tmp, (float*)d_out);
}